// Round 14
// baseline (498.659 us; speedup 1.0000x reference)
//
#include <hip/hip_runtime.h>

// Subtractor50Bit: A - B via two's complement, N rows x 50 bits ({0,1} floats).
// out = [result (N*50 floats), borrow (N floats)].
//
// R13 = R12 (= R9, session best: 124.2us dispatch, bench 436.8-438.8)
// with ONE variable changed: 512-thread blocks (8 waves/block) instead of
// 256 (4 waves/block), __launch_bounds__(512, 8) -> 4 blocks/CU = 32 wave
// slots.
// Evidence chain:
// - R12's profiled dispatch: 124.2us, FETCH 195MB (NT loads did NOT
//   bypass the MALL's read service -- traffic byte-identical to baseline;
//   the +23% came from the no-allocate path, not stream sequentiality).
//   604MB useful / 124us = 4.9 TB/s aggregate = 78% of copy ceiling.
// - NT regime has only run at 36% occupancy (R9/R12) or in the
//   traffic-amplifying persistent shell (R11: +100MB both streams).
// - R2 proves high occupancy (66%) in a NON-persistent contiguous-tile
//   shell does NOT amplify (FETCH exactly 195MB) -> untested clean cell:
//   NT x non-persistent x high-occ. The 36% cap looks like 4-wave-block
//   dispatch granularity; 8-wave blocks double resident read streams with
//   zero change to per-wave math or tile order.
// Signatures: FETCH ~195MB & WRITE ~199MB (>=250 => shell amplification
// returned => revert to R12, roofline); Occ >= 55%. Win: dur ~100-112us,
// bench ~415-425. Null (dur ~124 @ high occ): concurrency not the limiter
// -> roofline call next round.

constexpr int BITS = 50;
constexpr unsigned long long MASK50 = (1ULL << BITS) - 1ULL;

// clang-native vector: required by __builtin_nontemporal_load
// (HIP float2 is a struct); layout-identical to float2 (8B, 8B-aligned).
typedef float v2f __attribute__((ext_vector_type(2)));

__device__ inline unsigned long long shfl64(unsigned long long v, int src) {
    int lo = __shfl((int)(unsigned)(v & 0xffffffffULL), src, 64);
    int hi = __shfl((int)(unsigned)(v >> 32), src, 64);
    return ((unsigned long long)(unsigned)hi << 32) | (unsigned long long)(unsigned)lo;
}

// bit i -> bit 2i (valid for i < 32)
__device__ inline unsigned long long spread2(unsigned long long x) {
    x = (x | (x << 16)) & 0x0000FFFF0000FFFFULL;
    x = (x | (x << 8))  & 0x00FF00FF00FF00FFULL;
    x = (x | (x << 4))  & 0x0F0F0F0F0F0F0F0FULL;
    x = (x | (x << 2))  & 0x3333333333333333ULL;
    x = (x | (x << 1))  & 0x5555555555555555ULL;
    return x;
}

__global__ __launch_bounds__(512, 8) void Subtractor50Bit_kernel(
    const float* __restrict__ A, const float* __restrict__ B,
    float* __restrict__ out, int N)
{
    const int lane = threadIdx.x & 63;
    const int wv   = threadIdx.x >> 6;               // 0..7 (8 waves/block)
    const long long waveIdx = (long long)blockIdx.x * 8 + wv;
    const long long rowBase = waveIdx * 64;
    if (rowBase >= N) return;

    if (rowBase + 64 <= N) {
        // ---- full-wave fast path (64 rows, all lanes active) ----
        const long long eBase = rowBase * BITS;          // 3200 elements/wave
        const v2f* pa = (const v2f*)(A + eBase) + lane;
        const v2f* pb = (const v2f*)(B + eBase) + lane;

        // Phase 1: ALL loads issued first (independent, 512B/instr coalesced),
        // NONTEMPORAL: no L2/MALL allocation on the read path.
        v2f fa[25], fb[25];
        #pragma unroll
        for (int t = 0; t < 25; ++t) fa[t] = __builtin_nontemporal_load(pa + t * 64);
        #pragma unroll
        for (int t = 0; t < 25; ++t) fb[t] = __builtin_nontemporal_load(pb + t * 64);

        __builtin_amdgcn_sched_barrier(0);

        // Phase 2: ballots. Chunk t covers elements [128t, 128t+128):
        //   .x ballot = even-plane word t  (bit i = element 128t+2i)
        //   .y ballot = odd-plane  word t  (bit i = element 128t+2i+1)
        // E-words parked in lanes 0..24, O-words in lanes 32..56; others 0.
        unsigned long long wa = 0, wb = 0;
        const int  lane31 = lane & 31;
        const bool isLo   = lane < 32;
        #pragma unroll
        for (int t = 0; t < 25; ++t) {
            unsigned long long aE = __ballot(fa[t].x != 0.0f);
            unsigned long long aO = __ballot(fa[t].y != 0.0f);
            unsigned long long bE = __ballot(fb[t].x != 0.0f);
            unsigned long long bO = __ballot(fb[t].y != 0.0f);
            if (lane31 == t) {
                wa = isLo ? aE : aO;
                wb = isLo ? bE : bO;
            }
        }

        // Phase 3: per-lane row assembly; lane owns row (rowBase + lane).
        // Row's even bits = even-plane window [25*lane, 25*lane+25).
        const int p0 = 25 * lane;
        const int w0 = p0 >> 6;
        const int sh = p0 & 63;

        unsigned long long aE0 = shfl64(wa, w0);
        unsigned long long aE1 = shfl64(wa, w0 + 1);      // src>24 holds 0 (safe)
        unsigned long long aO0 = shfl64(wa, 32 + w0);
        unsigned long long aO1 = shfl64(wa, 33 + w0);
        unsigned long long bE0 = shfl64(wb, w0);
        unsigned long long bE1 = shfl64(wb, w0 + 1);
        unsigned long long bO0 = shfl64(wb, 32 + w0);
        unsigned long long bO1 = shfl64(wb, 33 + w0);

        unsigned long long evA = aE0 >> sh, odA = aO0 >> sh;
        unsigned long long evB = bE0 >> sh, odB = bO0 >> sh;
        if (sh > 39) {               // window straddles two plane words
            const int c = 64 - sh;   // in [1,24] here -> shifts well-defined
            evA |= aE1 << c; odA |= aO1 << c;
            evB |= bE1 << c; odB |= bO1 << c;
        }
        const unsigned long long M25 = (1ULL << 25) - 1ULL;
        evA &= M25; odA &= M25; evB &= M25; odB &= M25;

        unsigned long long av = spread2(evA) | (spread2(odA) << 1);
        unsigned long long bv = spread2(evB) | (spread2(odB) << 1);

        unsigned long long diff = (av - bv) & MASK50;     // A + ~B + 1 (mod 2^50)
        float borrow = (av < bv) ? 1.0f : 0.0f;           // 1 - carry_out

        // Phase 4: packed 8B stores, coalesced 512B/instr (plain stores;
        // NT-store was a measured regression). float2 q covers elements
        // [2q,2q+2), always one row (50 is even).
        unsigned long long* po = (unsigned long long*)(out + eBase);
        #pragma unroll
        for (int j = 0; j < 25; ++j) {
            int q = j * 64 + lane;            // float2 index in [0,1600)
            int r = q / 25;                   // owning local row (magic-mul)
            int k = 2 * (q - r * 25);         // bit index within row
            unsigned long long dr = shfl64(diff, r);
            unsigned long long t2 = dr >> k;
            po[q] = ((t2 & 1ULL) ? 0x000000003F800000ULL : 0ULL)
                  | ((t2 & 2ULL) ? 0x3F80000000000000ULL : 0ULL);
        }
        // borrow segment: naturally coalesced
        out[(long long)N * BITS + rowBase + lane] = borrow;
    } else {
        // ---- scalar tail path (partial wave; N%64!=0 safety net) ----
        long long r = rowBase + lane;
        if (r < N) {
            unsigned long long av = 0, bv = 0;
            for (int k = 0; k < BITS; ++k) {
                av |= (unsigned long long)(A[r * BITS + k] != 0.0f) << k;
                bv |= (unsigned long long)(B[r * BITS + k] != 0.0f) << k;
            }
            unsigned long long diff = (av - bv) & MASK50;
            for (int k = 0; k < BITS; ++k)
                out[r * BITS + k] = (float)((diff >> k) & 1ULL);
            out[(long long)N * BITS + r] = (av < bv) ? 1.0f : 0.0f;
        }
    }
}

extern "C" void kernel_launch(void* const* d_in, const int* in_sizes, int n_in,
                              void* d_out, int out_size, void* d_ws, size_t ws_size,
                              hipStream_t stream) {
    const float* A = (const float*)d_in[0];
    const float* B = (const float*)d_in[1];
    float* out = (float*)d_out;
    const int N = in_sizes[0] / BITS;          // 1,000,000

    const int waves  = (N + 63) / 64;          // one wave per 64 rows (15625)
    const int blocks = (waves + 7) / 8;        // 8 waves per 512-thread block
    Subtractor50Bit_kernel<<<blocks, 512, 0, stream>>>(A, B, out, N);
}

// Round 15
// 438.225 us; speedup vs baseline: 1.1379x; 1.1379x over previous
//
#include <hip/hip_runtime.h>

// Subtractor50Bit: A - B via two's complement, N rows x 50 bits ({0,1} floats).
// out = [result (N*50 floats), borrow (N floats)].
//
// R14 = R12 = R9 (verified session optimum: 124.2us profiled dispatch,
// bench 436.8-438.8). Restored after R13's pre-committed tripwire fired
// (8-wave blocks -> 32 waves/CU -> WRITE 394MB = ~2x output, FETCH +98MB:
// dirty-line eviction + RFO from 8192 concurrent streams vs 32MB L2).
//
// Complete session map (14 rounds, all counter-documented):
// - Allocating reads: 400MB inputs thrash the 256MB MALL -> scattered ~50%
//   residency -> ~2.6 TB/s cap immune to every CU-side knob (R0-R8, R10).
// - NT loads (this kernel): no-allocate read path -> 124us at compulsory
//   traffic (195MB fetch + 199MB write). 604MB/124us = 4.9 TB/s = 78% of
//   the 6.6 TB/s pure-stream fills -- mixed 2R:1W practical ceiling.
// - NT stores: -13% (R7b). A-cached/B-NT: relaxes to thrash equilibrium
//   (R10). Persistent shell or 32 waves/CU: +100-195MB amplification
//   (R8/R11/R13). LDS-DMA staging, double-buffered pipelining, fp-width,
//   max-occupancy: null or negative (R4/R6/R5/R8).
// ~12 waves/CU non-persistent + NT loads + plain stores is the optimum.

constexpr int BITS = 50;
constexpr unsigned long long MASK50 = (1ULL << BITS) - 1ULL;

// clang-native vector: required by __builtin_nontemporal_load
// (HIP float2 is a struct); layout-identical to float2 (8B, 8B-aligned).
typedef float v2f __attribute__((ext_vector_type(2)));

__device__ inline unsigned long long shfl64(unsigned long long v, int src) {
    int lo = __shfl((int)(unsigned)(v & 0xffffffffULL), src, 64);
    int hi = __shfl((int)(unsigned)(v >> 32), src, 64);
    return ((unsigned long long)(unsigned)hi << 32) | (unsigned long long)(unsigned)lo;
}

// bit i -> bit 2i (valid for i < 32)
__device__ inline unsigned long long spread2(unsigned long long x) {
    x = (x | (x << 16)) & 0x0000FFFF0000FFFFULL;
    x = (x | (x << 8))  & 0x00FF00FF00FF00FFULL;
    x = (x | (x << 4))  & 0x0F0F0F0F0F0F0F0FULL;
    x = (x | (x << 2))  & 0x3333333333333333ULL;
    x = (x | (x << 1))  & 0x5555555555555555ULL;
    return x;
}

__global__ __launch_bounds__(256) void Subtractor50Bit_kernel(
    const float* __restrict__ A, const float* __restrict__ B,
    float* __restrict__ out, int N)
{
    const int lane = threadIdx.x & 63;
    const int wv   = threadIdx.x >> 6;
    const long long waveIdx = (long long)blockIdx.x * 4 + wv;
    const long long rowBase = waveIdx * 64;
    if (rowBase >= N) return;

    if (rowBase + 64 <= N) {
        // ---- full-wave fast path (64 rows, all lanes active) ----
        const long long eBase = rowBase * BITS;          // 3200 elements/wave
        const v2f* pa = (const v2f*)(A + eBase) + lane;
        const v2f* pb = (const v2f*)(B + eBase) + lane;

        // Phase 1: ALL loads issued first (independent, 512B/instr coalesced),
        // NONTEMPORAL: no L2/MALL allocation on the read path.
        v2f fa[25], fb[25];
        #pragma unroll
        for (int t = 0; t < 25; ++t) fa[t] = __builtin_nontemporal_load(pa + t * 64);
        #pragma unroll
        for (int t = 0; t < 25; ++t) fb[t] = __builtin_nontemporal_load(pb + t * 64);

        __builtin_amdgcn_sched_barrier(0);

        // Phase 2: ballots. Chunk t covers elements [128t, 128t+128):
        //   .x ballot = even-plane word t  (bit i = element 128t+2i)
        //   .y ballot = odd-plane  word t  (bit i = element 128t+2i+1)
        // E-words parked in lanes 0..24, O-words in lanes 32..56; others 0.
        unsigned long long wa = 0, wb = 0;
        const int  lane31 = lane & 31;
        const bool isLo   = lane < 32;
        #pragma unroll
        for (int t = 0; t < 25; ++t) {
            unsigned long long aE = __ballot(fa[t].x != 0.0f);
            unsigned long long aO = __ballot(fa[t].y != 0.0f);
            unsigned long long bE = __ballot(fb[t].x != 0.0f);
            unsigned long long bO = __ballot(fb[t].y != 0.0f);
            if (lane31 == t) {
                wa = isLo ? aE : aO;
                wb = isLo ? bE : bO;
            }
        }

        // Phase 3: per-lane row assembly; lane owns row (rowBase + lane).
        // Row's even bits = even-plane window [25*lane, 25*lane+25).
        const int p0 = 25 * lane;
        const int w0 = p0 >> 6;
        const int sh = p0 & 63;

        unsigned long long aE0 = shfl64(wa, w0);
        unsigned long long aE1 = shfl64(wa, w0 + 1);      // src>24 holds 0 (safe)
        unsigned long long aO0 = shfl64(wa, 32 + w0);
        unsigned long long aO1 = shfl64(wa, 33 + w0);
        unsigned long long bE0 = shfl64(wb, w0);
        unsigned long long bE1 = shfl64(wb, w0 + 1);
        unsigned long long bO0 = shfl64(wb, 32 + w0);
        unsigned long long bO1 = shfl64(wb, 33 + w0);

        unsigned long long evA = aE0 >> sh, odA = aO0 >> sh;
        unsigned long long evB = bE0 >> sh, odB = bO0 >> sh;
        if (sh > 39) {               // window straddles two plane words
            const int c = 64 - sh;   // in [1,24] here -> shifts well-defined
            evA |= aE1 << c; odA |= aO1 << c;
            evB |= bE1 << c; odB |= bO1 << c;
        }
        const unsigned long long M25 = (1ULL << 25) - 1ULL;
        evA &= M25; odA &= M25; evB &= M25; odB &= M25;

        unsigned long long av = spread2(evA) | (spread2(odA) << 1);
        unsigned long long bv = spread2(evB) | (spread2(odB) << 1);

        unsigned long long diff = (av - bv) & MASK50;     // A + ~B + 1 (mod 2^50)
        float borrow = (av < bv) ? 1.0f : 0.0f;           // 1 - carry_out

        // Phase 4: packed 8B stores, coalesced 512B/instr (plain stores;
        // NT-store was a measured regression). float2 q covers elements
        // [2q,2q+2), always one row (50 is even).
        unsigned long long* po = (unsigned long long*)(out + eBase);
        #pragma unroll
        for (int j = 0; j < 25; ++j) {
            int q = j * 64 + lane;            // float2 index in [0,1600)
            int r = q / 25;                   // owning local row (magic-mul)
            int k = 2 * (q - r * 25);         // bit index within row
            unsigned long long dr = shfl64(diff, r);
            unsigned long long t2 = dr >> k;
            po[q] = ((t2 & 1ULL) ? 0x000000003F800000ULL : 0ULL)
                  | ((t2 & 2ULL) ? 0x3F80000000000000ULL : 0ULL);
        }
        // borrow segment: naturally coalesced
        out[(long long)N * BITS + rowBase + lane] = borrow;
    } else {
        // ---- scalar tail path (partial wave; N%64!=0 safety net) ----
        long long r = rowBase + lane;
        if (r < N) {
            unsigned long long av = 0, bv = 0;
            for (int k = 0; k < BITS; ++k) {
                av |= (unsigned long long)(A[r * BITS + k] != 0.0f) << k;
                bv |= (unsigned long long)(B[r * BITS + k] != 0.0f) << k;
            }
            unsigned long long diff = (av - bv) & MASK50;
            for (int k = 0; k < BITS; ++k)
                out[r * BITS + k] = (float)((diff >> k) & 1ULL);
            out[(long long)N * BITS + r] = (av < bv) ? 1.0f : 0.0f;
        }
    }
}

extern "C" void kernel_launch(void* const* d_in, const int* in_sizes, int n_in,
                              void* d_out, int out_size, void* d_ws, size_t ws_size,
                              hipStream_t stream) {
    const float* A = (const float*)d_in[0];
    const float* B = (const float*)d_in[1];
    float* out = (float*)d_out;
    const int N = in_sizes[0] / BITS;          // 1,000,000

    const int waves  = (N + 63) / 64;          // one wave per 64 rows
    const int blocks = (waves + 3) / 4;        // 4 waves per 256-thread block
    Subtractor50Bit_kernel<<<blocks, 256, 0, stream>>>(A, B, out, N);
}